// Round 13
// baseline (58.318 us; speedup 1.0000x reference)
//
#include <hip/hip_runtime.h>
#include <hip/hip_bf16.h>

#define NPTS 50000
#define NEG 0.2f
#define PSTRIDE 960
#define LOG2E 1.44269504088896340736f

typedef unsigned short u16;
typedef unsigned int   u32;

__device__ __forceinline__ float bf2f(u16 u){ return __uint_as_float(((u32)u) << 16); }
__device__ __forceinline__ u16 f2bf(float f){
  u32 w = __float_as_uint(f);
  return (u16)((w + 0x7fffu + ((w >> 16) & 1u)) >> 16);
}
__device__ __forceinline__ u32 pk2(float a, float b){
  __hip_bfloat162 h2 = __float22bfloat162_rn(float2{a, b});
  union { __hip_bfloat162 h; u32 u; } cv; cv.h = h2;
  return cv.u;
}
__device__ __forceinline__ float ulo(u32 g){ return __uint_as_float(g << 16); }
__device__ __forceinline__ float uhi(u32 g){ return __uint_as_float(g & 0xffff0000u); }
__device__ __forceinline__ float ldraw(const void* p, long i, int isf32){
  return isf32 ? ((const float*)p)[i] : bf2f(((const u16*)p)[i]);
}
__device__ __forceinline__ float wred(float v){
  #pragma unroll
  for (int m = 32; m > 0; m >>= 1) v += __shfl_xor(v, m, 64);
  return v;
}

__device__ int detect_isf32(const void* x){
  int lane = threadIdx.x & 63;
  const u16* p = (const u16*)x;
  int ze = 0, sane = 0;
  #pragma unroll
  for (int r = 0; r < 8; r++){
    int idx = lane * 8 + r;
    u16 u = p[idx];
    if ((idx & 1) == 0 && u == 0) ze++;
    float a = fabsf(bf2f(u));
    if (u == 0 || (a > 0.015625f && a < 64.f)) sane++;
  }
  #pragma unroll
  for (int m = 32; m > 0; m >>= 1){ ze += __shfl_xor(ze, m, 64); sane += __shfl_xor(sane, m, 64); }
  return (ze > 200) ? 1 : (sane > 460 ? 0 : 1);
}

template<int B> __device__ __forceinline__ int nbr_off(int t){
  if (B == 0){ constexpr int O[7]  = {0,-1,-3,-5,-7,-9,-11}; return O[t]; }
  else if (B == 1){ constexpr int O[7]  = {0,1,3,5,7,9,11}; return O[t]; }
  else { constexpr int O[13] = {0,-1,1,-3,3,-5,5,-7,7,-9,9,-11,11}; return O[t]; }
}

// ============ fold stage 1 (R12 form; also publishes dtype flag) ============
__global__ __launch_bounds__(256) void k_fold1(const void* x, const void* W2, const void* a2s,
                                               const void* a2d, const void* wfc, float* sAg,
                                               int* flag){
  __shared__ int s_flag;
  if (threadIdx.x < 64){ int f = detect_isf32(x); if (threadIdx.x == 0) s_flag = f; }
  __syncthreads();
  int isf32 = s_flag;
  if (blockIdx.x == 0 && blockIdx.y == 0 && threadIdx.x == 0) *flag = isf32;
  int kb = blockIdx.y, m = blockIdx.x;
  int hp = threadIdx.x >> 6, ch = threadIdx.x & 63;
  int c = hp * 64 + ch;
  float w = ldraw(W2, (long)kb * 65536 + (long)m * 256 + c, isf32);
  float s = wred(w * ldraw(a2s, kb * 256 + c, isf32));
  float d = wred(w * ldraw(a2d, kb * 256 + c, isf32));
  float f = wred(w * ldraw(wfc, kb * 64 + ch, isf32) * 0.25f);
  if (ch == 0){
    float* sA = sAg + (long)kb * 3072;
    sA[(0 * 4 + hp) * 256 + m] = s;
    sA[(1 * 4 + hp) * 256 + m] = d;
    sA[(2 * 4 + hp) * 256 + m] = f;
  }
}

// ============ fold stage 2 (R12 form) ============
__global__ __launch_bounds__(256) void k_fold2(const void* x, const void* W1, const void* a1s,
                                               const void* a1d, const void* b1, const void* b2,
                                               const void* wfc, const void* bfc,
                                               const float* sAg, float* P, const int* flag){
  int isf32 = *flag;
  int kb = blockIdx.y;
  int wid = blockIdx.x * 4 + (threadIdx.x >> 6);
  int ch = threadIdx.x & 63;
  float* Pp = P + kb * PSTRIDE;
  const float* sA = sAg + (long)kb * 3072;

  if (wid < 256){
    int hp = wid & 3, h = (wid >> 2) & 3, k = wid >> 4;
    int m = h * 64 + ch;
    float w = ldraw(W1, (long)kb * 4096 + k * 256 + m, isf32);
    float s = wred(w * sA[(0 * 4 + hp) * 256 + m]);
    float d = wred(w * sA[(1 * 4 + hp) * 256 + m]);
    float f = wred(w * sA[(2 * 4 + hp) * 256 + m]);
    if (ch == 0){ Pp[128 + wid] = s; Pp[384 + wid] = d; Pp[640 + wid] = f; }
  } else if (wid < 320){
    int j = wid - 256; int h = j & 3, k = j >> 2;
    int c = h * 64 + ch;
    float w = ldraw(W1, (long)kb * 4096 + k * 256 + c, isf32);
    float s = wred(w * ldraw(a1s, kb * 256 + c, isf32));
    float d = wred(w * ldraw(a1d, kb * 256 + c, isf32));
    if (ch == 0){ Pp[j] = s; Pp[64 + j] = d; }
  } else if (wid < 324){
    int hp = wid - 320;
    float a0 = 0.f, a1v = 0.f, a2v = 0.f;
    for (int it = 0; it < 4; it++){
      int m = it * 64 + ch;
      float bv = ldraw(b1, kb * 256 + m, isf32);
      a0  += bv * sA[(0 * 4 + hp) * 256 + m];
      a1v += bv * sA[(1 * 4 + hp) * 256 + m];
      a2v += bv * sA[(2 * 4 + hp) * 256 + m];
    }
    a0 = wred(a0); a1v = wred(a1v); a2v = wred(a2v);
    if (ch == 0){ Pp[896 + hp] = a0; Pp[900 + hp] = a1v; Pp[904 + hp] = a2v; }
  } else if (wid == 324){
    float a = wred(ldraw(b2, kb * 64 + ch, isf32) * ldraw(wfc, kb * 64 + ch, isf32));
    if (ch == 0) Pp[908] = a + ldraw(bfc, kb, isf32);
  }
}

// ============ k_feat: thread per (node, branch) -> two 64B records (F, G) ============
__global__ __launch_bounds__(256) void k_feat(const void* x, const float* P, const int* flag,
                                              u32* Fg){
  int node = blockIdx.x * 256 + threadIdx.x;
  if (node >= NPTS) return;
  int kb = blockIdx.y;
  int isf32 = *flag;
  const float* Pp = P + kb * PSTRIDE;

  float xv[16];
  if (isf32){
    const float4* xp = (const float4*)x + (long)node * 4;
    #pragma unroll
    for (int q = 0; q < 4; q++){
      float4 v = xp[q];
      xv[q*4] = v.x; xv[q*4+1] = v.y; xv[q*4+2] = v.z; xv[q*4+3] = v.w;
    }
  } else {
    const uint4* xp = (const uint4*)x + (long)node * 2;
    #pragma unroll
    for (int q = 0; q < 2; q++){
      uint4 v = xp[q];
      u32 wsv[4] = {v.x, v.y, v.z, v.w};
      #pragma unroll
      for (int r = 0; r < 4; r++){
        xv[q*8 + r*2]     = ulo(wsv[r]);
        xv[q*8 + r*2 + 1] = uhi(wsv[r]);
      }
    }
  }

  float s1[4] = {0,0,0,0}, d1[4] = {0,0,0,0};
  float s2[16], d2[16], f2[16];
  #pragma unroll
  for (int t = 0; t < 16; t++){ s2[t] = 0.f; d2[t] = 0.f; f2[t] = 0.f; }
  #pragma unroll
  for (int k = 0; k < 16; k++){
    float xk = xv[k];
    #pragma unroll
    for (int h = 0; h < 4; h++){
      s1[h] += xk * Pp[     k*4 + h];
      d1[h] += xk * Pp[64 + k*4 + h];
    }
    #pragma unroll
    for (int t = 0; t < 16; t++){
      s2[t] += xk * Pp[128 + k*16 + t];
      d2[t] += xk * Pp[384 + k*16 + t];
      f2[t] += xk * Pp[640 + k*16 + t];
    }
  }

  u32* F = Fg + (long)kb * NPTS * 16 + (long)node * 16;
  uint4 w0 = {__float_as_uint(s1[0] * LOG2E), __float_as_uint(s1[1] * LOG2E),
              __float_as_uint(s1[2] * LOG2E), __float_as_uint(s1[3] * LOG2E)};
  uint4 w1 = {__float_as_uint(d1[0] * LOG2E), __float_as_uint(d1[1] * LOG2E),
              __float_as_uint(d1[2] * LOG2E), __float_as_uint(d1[3] * LOG2E)};
  *(uint4*)(F + 0) = w0;
  *(uint4*)(F + 4) = w1;
  uint4 w2 = {pk2(s2[0], s2[1]), pk2(s2[2], s2[3]), pk2(s2[4], s2[5]), pk2(s2[6], s2[7])};
  uint4 w3 = {pk2(s2[8], s2[9]), pk2(s2[10], s2[11]), pk2(s2[12], s2[13]), pk2(s2[14], s2[15])};
  *(uint4*)(F + 8)  = w2;
  *(uint4*)(F + 12) = w3;
  u32* G = Fg + (long)3 * NPTS * 16 + (long)kb * NPTS * 16 + (long)node * 16;
  uint4 w4 = {pk2(d2[0], d2[1]), pk2(d2[2], d2[3]), pk2(d2[4], d2[5]), pk2(d2[6], d2[7])};
  uint4 w5 = {pk2(d2[8], d2[9]), pk2(d2[10], d2[11]), pk2(d2[12], d2[13]), pk2(d2[14], d2[15])};
  uint4 w6 = {pk2(f2[0], f2[1]), pk2(f2[2], f2[3]), pk2(f2[4], f2[5]), pk2(f2[6], f2[7])};
  uint4 w7 = {pk2(f2[8], f2[9]), pk2(f2[10], f2[11]), pk2(f2[12], f2[13]), pk2(f2[14], f2[15])};
  *(uint4*)(G + 0)  = w4;
  *(uint4*)(G + 4)  = w5;
  *(uint4*)(G + 8)  = w6;
  *(uint4*)(G + 12) = w7;
}

// ============ k_B: ONE thread per node, h-loop in-register, no shuffles ============
template<int BRANCH>
__device__ __forceinline__ void run_b(const u32* F, const u32* G, const float* Pp, int node,
                                      float* o2b){
  constexpr int CNT = (BRANCH == 2) ? 13 : 7;
  int jc[CNT]; u32 vmask = 0;
  #pragma unroll
  for (int tt = 0; tt < CNT; tt++){
    int j = node + nbr_off<BRANCH>(tt);
    jc[tt] = j < 0 ? 0 : (j >= NPTS ? NPTS - 1 : j);
    if ((unsigned)j < NPTS) vmask |= (1u << tt);
  }
  uint4 advv = *(const uint4*)(F + (long)node * 16 + 4);
  float advs[4] = {__uint_as_float(advv.x), __uint_as_float(advv.y),
                   __uint_as_float(advv.z), __uint_as_float(advv.w)};
  float ts[4] = {0,0,0,0}, td[4] = {0,0,0,0}, tf[4] = {0,0,0,0};

  #pragma unroll
  for (int h = 0; h < 4; h++){
    float adv = advs[h];
    float e[CNT];
    float mx = -3e38f;
    #pragma unroll
    for (int tt = 0; tt < CNT; tt++){
      float v = __uint_as_float(F[(long)jc[tt] * 16 + h]) + adv;
      v = v > 0.f ? v : NEG * v;
      e[tt] = (vmask & (1u << tt)) ? v : -3e38f;
      mx = fmaxf(mx, e[tt]);
    }
    float den = 0.f;
    float us[4] = {0,0,0,0}, ud[4] = {0,0,0,0}, uf[4] = {0,0,0,0};
    #pragma unroll
    for (int tt = 0; tt < CNT; tt++){
      float ex = exp2f(e[tt] - mx);
      den += ex;
      long fb = (long)jc[tt] * 16;
      uint2 gs = *(const uint2*)(F + fb + 8 + h * 2);
      uint2 gd = *(const uint2*)(G + fb + h * 2);
      uint2 gf = *(const uint2*)(G + fb + 8 + h * 2);
      us[0] += ex * ulo(gs.x); us[1] += ex * uhi(gs.x);
      us[2] += ex * ulo(gs.y); us[3] += ex * uhi(gs.y);
      ud[0] += ex * ulo(gd.x); ud[1] += ex * uhi(gd.x);
      ud[2] += ex * ulo(gd.y); ud[3] += ex * uhi(gd.y);
      uf[0] += ex * ulo(gf.x); uf[1] += ex * uhi(gf.x);
      uf[2] += ex * ulo(gf.y); uf[3] += ex * uhi(gf.y);
    }
    float inv = 1.f / den;
    #pragma unroll
    for (int hp = 0; hp < 4; hp++){
      ts[hp] += us[hp] * inv;
      td[hp] += ud[hp] * inv;
      tf[hp] += uf[hp] * inv;
    }
  }
  float* ob = o2b + (long)node * 12;
  *(float4*)(ob + 0) = make_float4((ts[0] + Pp[896]) * LOG2E, (ts[1] + Pp[897]) * LOG2E,
                                   (ts[2] + Pp[898]) * LOG2E, (ts[3] + Pp[899]) * LOG2E);
  *(float4*)(ob + 4) = make_float4((td[0] + Pp[900]) * LOG2E, (td[1] + Pp[901]) * LOG2E,
                                   (td[2] + Pp[902]) * LOG2E, (td[3] + Pp[903]) * LOG2E);
  *(float4*)(ob + 8) = make_float4(tf[0] + Pp[904], tf[1] + Pp[905],
                                   tf[2] + Pp[906], tf[3] + Pp[907]);
}

__global__ __launch_bounds__(256) void k_B(const u32* Fg, const float* P, float* o2g){
  int node = blockIdx.x * 256 + threadIdx.x;
  if (node >= NPTS) return;
  int br = blockIdx.y;
  const u32* F = Fg + (long)br * NPTS * 16;
  const u32* G = Fg + (long)3 * NPTS * 16 + (long)br * NPTS * 16;
  const float* Pp = P + br * PSTRIDE;
  float* o2b = o2g + (long)br * NPTS * 12;
  if (br == 0)      run_b<0>(F, G, Pp, node, o2b);
  else if (br == 1) run_b<1>(F, G, Pp, node, o2b);
  else              run_b<2>(F, G, Pp, node, o2b);
}

// ============ k_C: ONE thread per node, hp-loop, no shuffles ============
template<int BRANCH>
__device__ __forceinline__ void run_c(const float* ob, const float* Pp, int isf32, int node,
                                      void* out){
  constexpr int CNT = (BRANCH == 2) ? 13 : 7;
  int jc[CNT]; u32 vmask = 0;
  #pragma unroll
  for (int tt = 0; tt < CNT; tt++){
    int j = node + nbr_off<BRANCH>(tt);
    jc[tt] = j < 0 ? 0 : (j >= NPTS ? NPTS - 1 : j);
    if ((unsigned)j < NPTS) vmask |= (1u << tt);
  }
  float4 advq = *(const float4*)(ob + (long)node * 12 + 4);
  float advs[4] = {advq.x, advq.y, advq.z, advq.w};
  float r = Pp[908];
  #pragma unroll
  for (int hp = 0; hp < 4; hp++){
    float adv = advs[hp];
    float e[CNT];
    float mx = -3e38f;
    #pragma unroll
    for (int tt = 0; tt < CNT; tt++){
      float v = ob[(long)jc[tt] * 12 + hp] + adv;
      v = v > 0.f ? v : NEG * v;
      e[tt] = (vmask & (1u << tt)) ? v : -3e38f;
      mx = fmaxf(mx, e[tt]);
    }
    float den = 0.f, sm = 0.f;
    #pragma unroll
    for (int tt = 0; tt < CNT; tt++){
      float ex = exp2f(e[tt] - mx);
      den += ex;
      sm += ex * ob[(long)jc[tt] * 12 + 8 + hp];
    }
    r += sm / den;
  }
  long oi = (long)BRANCH * NPTS + node;
  if (isf32) ((float*)out)[oi] = r;
  else       ((u16*)out)[oi]  = f2bf(r);
}

__global__ __launch_bounds__(256) void k_C(const float* o2g, const float* P, const int* flag,
                                           void* out){
  int node = blockIdx.x * 256 + threadIdx.x;
  if (node >= NPTS) return;
  int br = blockIdx.y;
  int isf32 = *flag;
  const float* ob = o2g + (long)br * NPTS * 12;
  const float* Pp = P + br * PSTRIDE;
  if (br == 0)      run_c<0>(ob, Pp, isf32, node, out);
  else if (br == 1) run_c<1>(ob, Pp, isf32, node, out);
  else              run_c<2>(ob, Pp, isf32, node, out);
}

extern "C" void kernel_launch(void* const* d_in, const int* in_sizes, int n_in,
                              void* d_out, int out_size, void* d_ws, size_t ws_size,
                              hipStream_t stream){
  char* ws = (char*)d_ws;
  size_t off = 0;
  auto take = [&](size_t b) -> size_t { size_t r = off; off += (b + 255) & ~(size_t)255; return r; };

  float* sAg  = (float*)(ws + take((size_t)3 * 3072 * 4));
  float* P    = (float*)(ws + take((size_t)3 * PSTRIDE * 4));
  int*   flag = (int*)(ws + take(4));
  u32*   Fg   = (u32*)(ws + take((size_t)6 * NPTS * 16 * 4));
  float* o2g  = (float*)(ws + take((size_t)3 * NPTS * 12 * 4));

  const void* x   = d_in[0];
  const void* W1  = d_in[4];
  const void* a1s = d_in[5];
  const void* a1d = d_in[6];
  const void* b1  = d_in[7];
  const void* W2  = d_in[8];
  const void* a2s = d_in[9];
  const void* a2d = d_in[10];
  const void* b2  = d_in[11];
  const void* wfc = d_in[12];
  const void* bfc = d_in[13];

  k_fold1<<<dim3(256, 3), 256, 0, stream>>>(x, W2, a2s, a2d, wfc, sAg, flag);
  k_fold2<<<dim3(82, 3), 256, 0, stream>>>(x, W1, a1s, a1d, b1, b2, wfc, bfc, sAg, P, flag);
  k_feat<<<dim3((NPTS + 255) / 256, 3), 256, 0, stream>>>(x, P, flag, Fg);
  k_B<<<dim3((NPTS + 255) / 256, 3), 256, 0, stream>>>(Fg, P, o2g);
  k_C<<<dim3((NPTS + 255) / 256, 3), 256, 0, stream>>>(o2g, P, flag, d_out);
}

// Round 14
// 52.939 us; speedup vs baseline: 1.1016x; 1.1016x over previous
//
#include <hip/hip_runtime.h>
#include <hip/hip_bf16.h>

#define NPTS 50000
#define NEG 0.2f
#define PSTRIDE 960
#define LOG2E 1.44269504088896340736f

typedef unsigned short u16;
typedef unsigned int   u32;

__device__ __forceinline__ float bf2f(u16 u){ return __uint_as_float(((u32)u) << 16); }
__device__ __forceinline__ u16 f2bf(float f){
  u32 w = __float_as_uint(f);
  return (u16)((w + 0x7fffu + ((w >> 16) & 1u)) >> 16);
}
__device__ __forceinline__ u32 pk2(float a, float b){
  __hip_bfloat162 h2 = __float22bfloat162_rn(float2{a, b});
  union { __hip_bfloat162 h; u32 u; } cv; cv.h = h2;
  return cv.u;
}
__device__ __forceinline__ float ulo(u32 g){ return __uint_as_float(g << 16); }
__device__ __forceinline__ float uhi(u32 g){ return __uint_as_float(g & 0xffff0000u); }
__device__ __forceinline__ float ldraw(const void* p, long i, int isf32){
  return isf32 ? ((const float*)p)[i] : bf2f(((const u16*)p)[i]);
}
__device__ __forceinline__ float wred(float v){
  #pragma unroll
  for (int m = 32; m > 0; m >>= 1) v += __shfl_xor(v, m, 64);
  return v;
}

__device__ int detect_isf32(const void* x){
  int lane = threadIdx.x & 63;
  const u16* p = (const u16*)x;
  int ze = 0, sane = 0;
  #pragma unroll
  for (int r = 0; r < 8; r++){
    int idx = lane * 8 + r;
    u16 u = p[idx];
    if ((idx & 1) == 0 && u == 0) ze++;
    float a = fabsf(bf2f(u));
    if (u == 0 || (a > 0.015625f && a < 64.f)) sane++;
  }
  #pragma unroll
  for (int m = 32; m > 0; m >>= 1){ ze += __shfl_xor(ze, m, 64); sane += __shfl_xor(sane, m, 64); }
  return (ze > 200) ? 1 : (sane > 460 ? 0 : 1);
}

template<int B> __device__ __forceinline__ int nbr_off(int t){
  if (B == 0){ constexpr int O[7]  = {0,-1,-3,-5,-7,-9,-11}; return O[t]; }
  else if (B == 1){ constexpr int O[7]  = {0,1,3,5,7,9,11}; return O[t]; }
  else { constexpr int O[13] = {0,-1,1,-3,3,-5,5,-7,7,-9,9,-11,11}; return O[t]; }
}

// ============ fold stage 1 (also publishes dtype flag) ============
__global__ __launch_bounds__(256) void k_fold1(const void* x, const void* W2, const void* a2s,
                                               const void* a2d, const void* wfc, float* sAg,
                                               int* flag){
  __shared__ int s_flag;
  if (threadIdx.x < 64){ int f = detect_isf32(x); if (threadIdx.x == 0) s_flag = f; }
  __syncthreads();
  int isf32 = s_flag;
  if (blockIdx.x == 0 && blockIdx.y == 0 && threadIdx.x == 0) *flag = isf32;
  int kb = blockIdx.y, m = blockIdx.x;
  int hp = threadIdx.x >> 6, ch = threadIdx.x & 63;
  int c = hp * 64 + ch;
  float w = ldraw(W2, (long)kb * 65536 + (long)m * 256 + c, isf32);
  float s = wred(w * ldraw(a2s, kb * 256 + c, isf32));
  float d = wred(w * ldraw(a2d, kb * 256 + c, isf32));
  float f = wred(w * ldraw(wfc, kb * 64 + ch, isf32) * 0.25f);
  if (ch == 0){
    float* sA = sAg + (long)kb * 3072;
    sA[(0 * 4 + hp) * 256 + m] = s;
    sA[(1 * 4 + hp) * 256 + m] = d;
    sA[(2 * 4 + hp) * 256 + m] = f;
  }
}

// ============ fold stage 2 ============
__global__ __launch_bounds__(256) void k_fold2(const void* x, const void* W1, const void* a1s,
                                               const void* a1d, const void* b1, const void* b2,
                                               const void* wfc, const void* bfc,
                                               const float* sAg, float* P, const int* flag){
  int isf32 = *flag;
  int kb = blockIdx.y;
  int wid = blockIdx.x * 4 + (threadIdx.x >> 6);
  int ch = threadIdx.x & 63;
  float* Pp = P + kb * PSTRIDE;
  const float* sA = sAg + (long)kb * 3072;

  if (wid < 256){
    int hp = wid & 3, h = (wid >> 2) & 3, k = wid >> 4;
    int m = h * 64 + ch;
    float w = ldraw(W1, (long)kb * 4096 + k * 256 + m, isf32);
    float s = wred(w * sA[(0 * 4 + hp) * 256 + m]);
    float d = wred(w * sA[(1 * 4 + hp) * 256 + m]);
    float f = wred(w * sA[(2 * 4 + hp) * 256 + m]);
    if (ch == 0){ Pp[128 + wid] = s; Pp[384 + wid] = d; Pp[640 + wid] = f; }
  } else if (wid < 320){
    int j = wid - 256; int h = j & 3, k = j >> 2;
    int c = h * 64 + ch;
    float w = ldraw(W1, (long)kb * 4096 + k * 256 + c, isf32);
    float s = wred(w * ldraw(a1s, kb * 256 + c, isf32));
    float d = wred(w * ldraw(a1d, kb * 256 + c, isf32));
    if (ch == 0){ Pp[j] = s; Pp[64 + j] = d; }
  } else if (wid < 324){
    int hp = wid - 320;
    float a0 = 0.f, a1v = 0.f, a2v = 0.f;
    for (int it = 0; it < 4; it++){
      int m = it * 64 + ch;
      float bv = ldraw(b1, kb * 256 + m, isf32);
      a0  += bv * sA[(0 * 4 + hp) * 256 + m];
      a1v += bv * sA[(1 * 4 + hp) * 256 + m];
      a2v += bv * sA[(2 * 4 + hp) * 256 + m];
    }
    a0 = wred(a0); a1v = wred(a1v); a2v = wred(a2v);
    if (ch == 0){ Pp[896 + hp] = a0; Pp[900 + hp] = a1v; Pp[904 + hp] = a2v; }
  } else if (wid == 324){
    float a = wred(ldraw(b2, kb * 64 + ch, isf32) * ldraw(wfc, kb * 64 + ch, isf32));
    if (ch == 0) Pp[908] = a + ldraw(bfc, kb, isf32);
  }
}

// ============ k_feat: thread per (node, branch) -> two 64B records (F, G) ============
__global__ __launch_bounds__(256) void k_feat(const void* x, const float* P, const int* flag,
                                              u32* Fg){
  int node = blockIdx.x * 256 + threadIdx.x;
  if (node >= NPTS) return;
  int kb = blockIdx.y;
  int isf32 = *flag;
  const float* Pp = P + kb * PSTRIDE;

  float xv[16];
  if (isf32){
    const float4* xp = (const float4*)x + (long)node * 4;
    #pragma unroll
    for (int q = 0; q < 4; q++){
      float4 v = xp[q];
      xv[q*4] = v.x; xv[q*4+1] = v.y; xv[q*4+2] = v.z; xv[q*4+3] = v.w;
    }
  } else {
    const uint4* xp = (const uint4*)x + (long)node * 2;
    #pragma unroll
    for (int q = 0; q < 2; q++){
      uint4 v = xp[q];
      u32 wsv[4] = {v.x, v.y, v.z, v.w};
      #pragma unroll
      for (int r = 0; r < 4; r++){
        xv[q*8 + r*2]     = ulo(wsv[r]);
        xv[q*8 + r*2 + 1] = uhi(wsv[r]);
      }
    }
  }

  float s1[4] = {0,0,0,0}, d1[4] = {0,0,0,0};
  float s2[16], d2[16], f2[16];
  #pragma unroll
  for (int t = 0; t < 16; t++){ s2[t] = 0.f; d2[t] = 0.f; f2[t] = 0.f; }
  #pragma unroll
  for (int k = 0; k < 16; k++){
    float xk = xv[k];
    #pragma unroll
    for (int h = 0; h < 4; h++){
      s1[h] += xk * Pp[     k*4 + h];
      d1[h] += xk * Pp[64 + k*4 + h];
    }
    #pragma unroll
    for (int t = 0; t < 16; t++){
      s2[t] += xk * Pp[128 + k*16 + t];
      d2[t] += xk * Pp[384 + k*16 + t];
      f2[t] += xk * Pp[640 + k*16 + t];
    }
  }

  u32* F = Fg + (long)kb * NPTS * 16 + (long)node * 16;
  uint4 w0 = {__float_as_uint(s1[0] * LOG2E), __float_as_uint(s1[1] * LOG2E),
              __float_as_uint(s1[2] * LOG2E), __float_as_uint(s1[3] * LOG2E)};
  uint4 w1 = {__float_as_uint(d1[0] * LOG2E), __float_as_uint(d1[1] * LOG2E),
              __float_as_uint(d1[2] * LOG2E), __float_as_uint(d1[3] * LOG2E)};
  *(uint4*)(F + 0) = w0;
  *(uint4*)(F + 4) = w1;
  uint4 w2 = {pk2(s2[0], s2[1]), pk2(s2[2], s2[3]), pk2(s2[4], s2[5]), pk2(s2[6], s2[7])};
  uint4 w3 = {pk2(s2[8], s2[9]), pk2(s2[10], s2[11]), pk2(s2[12], s2[13]), pk2(s2[14], s2[15])};
  *(uint4*)(F + 8)  = w2;
  *(uint4*)(F + 12) = w3;
  u32* G = Fg + (long)3 * NPTS * 16 + (long)kb * NPTS * 16 + (long)node * 16;
  uint4 w4 = {pk2(d2[0], d2[1]), pk2(d2[2], d2[3]), pk2(d2[4], d2[5]), pk2(d2[6], d2[7])};
  uint4 w5 = {pk2(d2[8], d2[9]), pk2(d2[10], d2[11]), pk2(d2[12], d2[13]), pk2(d2[14], d2[15])};
  uint4 w6 = {pk2(f2[0], f2[1]), pk2(f2[2], f2[3]), pk2(f2[4], f2[5]), pk2(f2[6], f2[7])};
  uint4 w7 = {pk2(f2[8], f2[9]), pk2(f2[10], f2[11]), pk2(f2[12], f2[13]), pk2(f2[14], f2[15])};
  *(uint4*)(G + 0)  = w4;
  *(uint4*)(G + 4)  = w5;
  *(uint4*)(G + 8)  = w6;
  *(uint4*)(G + 12) = w7;
}

// ============ k_B: thread per (node, L1-head h); no LDS, no barriers ============
template<int BRANCH>
__device__ __forceinline__ void run_b(const u32* F, const u32* G, const float* Pp, long t,
                                      float* o2b){
  constexpr int CNT = (BRANCH == 2) ? 13 : 7;
  int node = (int)(t >> 2), h = (int)(t & 3);
  if (node >= NPTS) return;
  float adv = __uint_as_float(F[(long)node * 16 + 4 + h]);

  float e[CNT]; int jc[CNT];
  float mx = -3e38f;
  #pragma unroll
  for (int tt = 0; tt < CNT; tt++){
    int off = nbr_off<BRANCH>(tt);
    int j = node + off;
    int jj = j < 0 ? 0 : (j >= NPTS ? NPTS - 1 : j);
    jc[tt] = jj;
    float v = __uint_as_float(F[(long)jj * 16 + h]) + adv;
    v = v > 0.f ? v : NEG * v;
    e[tt] = ((unsigned)j < NPTS) ? v : -3e38f;
    mx = fmaxf(mx, e[tt]);
  }
  float den = 0.f;
  float ts[4] = {0,0,0,0}, td[4] = {0,0,0,0}, tf[4] = {0,0,0,0};
  #pragma unroll
  for (int tt = 0; tt < CNT; tt++){
    float ex = exp2f(e[tt] - mx);
    den += ex;
    long fb = (long)jc[tt] * 16;
    uint2 gs = *(const uint2*)(F + fb + 8 + h * 2);
    uint2 gd = *(const uint2*)(G + fb + h * 2);
    uint2 gf = *(const uint2*)(G + fb + 8 + h * 2);
    ts[0] += ex * ulo(gs.x); ts[1] += ex * uhi(gs.x);
    ts[2] += ex * ulo(gs.y); ts[3] += ex * uhi(gs.y);
    td[0] += ex * ulo(gd.x); td[1] += ex * uhi(gd.x);
    td[2] += ex * ulo(gd.y); td[3] += ex * uhi(gd.y);
    tf[0] += ex * ulo(gf.x); tf[1] += ex * uhi(gf.x);
    tf[2] += ex * ulo(gf.y); tf[3] += ex * uhi(gf.y);
  }
  float inv = 1.f / den;
  #pragma unroll
  for (int hp = 0; hp < 4; hp++){
    ts[hp] *= inv; td[hp] *= inv; tf[hp] *= inv;
    ts[hp] += __shfl_xor(ts[hp], 1, 64); ts[hp] += __shfl_xor(ts[hp], 2, 64);
    td[hp] += __shfl_xor(td[hp], 1, 64); td[hp] += __shfl_xor(td[hp], 2, 64);
    tf[hp] += __shfl_xor(tf[hp], 1, 64); tf[hp] += __shfl_xor(tf[hp], 2, 64);
  }
  if (h == 0){
    float* ob = o2b + (long)node * 12;
    *(float4*)(ob + 0) = make_float4((ts[0] + Pp[896]) * LOG2E, (ts[1] + Pp[897]) * LOG2E,
                                     (ts[2] + Pp[898]) * LOG2E, (ts[3] + Pp[899]) * LOG2E);
    *(float4*)(ob + 4) = make_float4((td[0] + Pp[900]) * LOG2E, (td[1] + Pp[901]) * LOG2E,
                                     (td[2] + Pp[902]) * LOG2E, (td[3] + Pp[903]) * LOG2E);
    *(float4*)(ob + 8) = make_float4(tf[0] + Pp[904], tf[1] + Pp[905],
                                     tf[2] + Pp[906], tf[3] + Pp[907]);
  }
}

__global__ __launch_bounds__(256) void k_B(const u32* Fg, const float* P, float* o2g){
  long t = (long)blockIdx.x * 256 + threadIdx.x;
  int br = blockIdx.y;
  const u32* F = Fg + (long)br * NPTS * 16;
  const u32* G = Fg + (long)3 * NPTS * 16 + (long)br * NPTS * 16;
  const float* Pp = P + br * PSTRIDE;
  float* o2b = o2g + (long)br * NPTS * 12;
  if (br == 0)      run_b<0>(F, G, Pp, t, o2b);
  else if (br == 1) run_b<1>(F, G, Pp, t, o2b);
  else              run_b<2>(F, G, Pp, t, o2b);
}

// ============ k_C: thread per (node, L2-head hp); no LDS, no barriers ============
template<int BRANCH>
__device__ __forceinline__ void run_c(const float* ob, const float* Pp, int isf32, long t,
                                      void* out){
  constexpr int CNT = (BRANCH == 2) ? 13 : 7;
  int node = (int)(t >> 2), hp = (int)(t & 3);
  if (node >= NPTS) return;
  float adv = ob[(long)node * 12 + 4 + hp];
  float e[CNT]; int jc[CNT];
  float mx = -3e38f;
  #pragma unroll
  for (int tt = 0; tt < CNT; tt++){
    int off = nbr_off<BRANCH>(tt);
    int j = node + off;
    int jj = j < 0 ? 0 : (j >= NPTS ? NPTS - 1 : j);
    jc[tt] = jj;
    float v = ob[(long)jj * 12 + hp] + adv;
    v = v > 0.f ? v : NEG * v;
    e[tt] = ((unsigned)j < NPTS) ? v : -3e38f;
    mx = fmaxf(mx, e[tt]);
  }
  float den = 0.f, sm = 0.f;
  #pragma unroll
  for (int tt = 0; tt < CNT; tt++){
    float ex = exp2f(e[tt] - mx);
    den += ex;
    sm += ex * ob[(long)jc[tt] * 12 + 8 + hp];
  }
  float r = sm / den;
  r += __shfl_xor(r, 1, 64);
  r += __shfl_xor(r, 2, 64);
  if (hp == 0){
    float o = r + Pp[908];
    long oi = (long)BRANCH * NPTS + node;
    if (isf32) ((float*)out)[oi] = o;
    else       ((u16*)out)[oi]  = f2bf(o);
  }
}

__global__ __launch_bounds__(256) void k_C(const float* o2g, const float* P, const int* flag,
                                           void* out){
  long t = (long)blockIdx.x * 256 + threadIdx.x;
  int br = blockIdx.y;
  int isf32 = *flag;
  const float* ob = o2g + (long)br * NPTS * 12;
  const float* Pp = P + br * PSTRIDE;
  if (br == 0)      run_c<0>(ob, Pp, isf32, t, out);
  else if (br == 1) run_c<1>(ob, Pp, isf32, t, out);
  else              run_c<2>(ob, Pp, isf32, t, out);
}

extern "C" void kernel_launch(void* const* d_in, const int* in_sizes, int n_in,
                              void* d_out, int out_size, void* d_ws, size_t ws_size,
                              hipStream_t stream){
  char* ws = (char*)d_ws;
  size_t off = 0;
  auto take = [&](size_t b) -> size_t { size_t r = off; off += (b + 255) & ~(size_t)255; return r; };

  float* sAg  = (float*)(ws + take((size_t)3 * 3072 * 4));
  float* P    = (float*)(ws + take((size_t)3 * PSTRIDE * 4));
  int*   flag = (int*)(ws + take(4));
  u32*   Fg   = (u32*)(ws + take((size_t)6 * NPTS * 16 * 4));
  float* o2g  = (float*)(ws + take((size_t)3 * NPTS * 12 * 4));

  const void* x   = d_in[0];
  const void* W1  = d_in[4];
  const void* a1s = d_in[5];
  const void* a1d = d_in[6];
  const void* b1  = d_in[7];
  const void* W2  = d_in[8];
  const void* a2s = d_in[9];
  const void* a2d = d_in[10];
  const void* b2  = d_in[11];
  const void* wfc = d_in[12];
  const void* bfc = d_in[13];

  k_fold1<<<dim3(256, 3), 256, 0, stream>>>(x, W2, a2s, a2d, wfc, sAg, flag);
  k_fold2<<<dim3(82, 3), 256, 0, stream>>>(x, W1, a1s, a1d, b1, b2, wfc, bfc, sAg, P, flag);
  k_feat<<<dim3((NPTS + 255) / 256, 3), 256, 0, stream>>>(x, P, flag, Fg);
  k_B<<<dim3((NPTS * 4 + 255) / 256, 3), 256, 0, stream>>>(Fg, P, o2g);
  k_C<<<dim3((NPTS * 4 + 255) / 256, 3), 256, 0, stream>>>(o2g, P, flag, d_out);
}